// Round 1
// 126.470 us; speedup vs baseline: 1.0402x; 1.0402x over previous
//
#include <hip/hip_runtime.h>
#include <hip/hip_bf16.h>
#include <math.h>

// CrossGeometricStructureEmbedding, round 8.
// R7 post-mortem: MfmaUtil 37.6 == VALUBusy 37.8, sum 75%, HBM 0.9% -> not
// BW-bound; 25% of cycles nothing issues. Root cause: 2 waves/SIMD (256-thr
// blocks, 230-VGPR waves) gives no latency hiding for lgkmcnt waits, trans
// chains, and barrier drains. R8: 8-wave (512-thr) blocks, 32 cols/wave ->
// W strip 64 VGPRs + acc 32 fits the 128-reg cap of 4 waves/SIMD
// (__launch_bounds__(512,4); still 2 independent blocks/CU for anti-phase
// overlap). Same dbuf E + fused fill + d-then-a phase structure. VALU trims:
// XOR-decomposed swizzle addressing (1 v_xor per ds access) and fract removal
// (v_sin/v_cos valid to +-256 revolutions; our args < 10; fract adds no
// precision). LDS 78.6KB unchanged.

typedef __attribute__((ext_vector_type(8))) short short8;
typedef __attribute__((ext_vector_type(16))) float f32x16;
typedef __attribute__((ext_vector_type(4))) unsigned int uint4v;

#define HH 256
#define P_PTS 8
#define NPTS 4096

__device__ __forceinline__ unsigned short f2bf(float f) {
    union { float f; unsigned int u; } v; v.f = f;
    unsigned int r = v.u + 0x7fffu + ((v.u >> 16) & 1u);  // RNE
    return (unsigned short)(r >> 16);
}

__device__ __forceinline__ unsigned int pack_sc(float s, float c) {
    union { __hip_bfloat162 h; unsigned int u; } v;
    v.h = __float22bfloat162_rn(make_float2(s, c));  // low = sin, high = cos
    return v.u;
}

__global__ __launch_bounds__(256)
void prep_w_kernel(const float* __restrict__ Wa, const float* __restrict__ Wd,
                   unsigned short* __restrict__ wbf) {
    int i = blockIdx.x * 256 + threadIdx.x;
    if (i < HH * HH) {
        wbf[i] = f2bf(Wd[i]);             // [0, 65536): Wd bf16
        wbf[HH * HH + i] = f2bf(Wa[i]);   // [65536, 131072): Wa bf16
    }
}

// E swizzle: chunk ch (16B) of row r lives at byte offset
//   r*512 + ((ch ^ (r&7)) << 4)  ==  (r*512 ^ ((r&7)<<4)) ^ (ch<<4)
// (r*512 has no bits <9; chunk_off<<4 < 512 -> no carries; XOR of shifted
// values == shift of XOR). ch<<4 further splits into disjoint-bit XORs of
// its compile-time and runtime parts, so each access is base ^ const.

__global__ __launch_bounds__(512, 4)
void cgse_main(const float* __restrict__ points,
               const float* __restrict__ anchors,
               const unsigned short* __restrict__ wbf,
               const float* __restrict__ ba,
               const float* __restrict__ bd,
               float* __restrict__ out) {
    __shared__ __align__(16) unsigned short E[2][64 * HH];  // 64 KB dbuf
    __shared__ float dms[P_PTS][HH];                        // 8 KB d-pass maxes
    __shared__ float xsd[P_PTS][64], xsa[P_PTS][64];        // 4 KB
    __shared__ float anch[192];

    const int tid = threadIdx.x;
    const int wave = tid >> 6, lane = tid & 63;
    const int l5 = lane & 31, half = lane >> 5;
    const int base = blockIdx.x * P_PTS;
    const int col = wave * 32 + l5;  // this wave's output column (one of 256)

    // ---- anchors, then geometry: 512 tasks / 512 threads (pt = wave, k = lane)
    if (tid < 192) anch[tid] = anchors[tid];
    __syncthreads();
    {
        const int k2 = (lane + 1) & 63;
        const int pn = base + wave;
        const float px = points[pn * 3 + 0], py = points[pn * 3 + 1], pz = points[pn * 3 + 2];
        const float r1x = px - anch[lane * 3 + 0];
        const float r1y = py - anch[lane * 3 + 1];
        const float r1z = pz - anch[lane * 3 + 2];
        const float r2x = px - anch[k2 * 3 + 0];
        const float r2y = py - anch[k2 * 3 + 1];
        const float r2z = pz - anch[k2 * 3 + 2];
        xsd[wave][lane] = sqrtf(r1x * r1x + r1y * r1y + r1z * r1z) * 5.0f;  // /SIGMA_D
        const float cx = r1y * r2z - r1z * r2y;
        const float cy = r1z * r2x - r1x * r2z;
        const float cz = r1x * r2y - r1y * r2x;
        const float sv = sqrtf(cx * cx + cy * cy + cz * cz);
        const float cv = r1x * r2x + r1y * r2y + r1z * r2z;
        xsa[wave][lane] = atan2f(sv, cv) * 3.8197186342054885f;  // *180/(15*pi)
    }

    const float bias = ba[col] + bd[col];

    // ---- fill constants: omega_i = x * rho^i / 2pi, rho = 1e4^(-1/128) = 10^(-1/32).
    // wave fills chunks 4w..4w+3; chunk ch covers pairs 4ch..4ch+3 ->
    // chunk factor 10^(-ch/8) = 10^(-w/2) * 10^(-c/8).
    const float cw = 0.15915494309189535f * __expf(-(float)wave * 1.1512925464970227f);

    // XOR-decomposed address bases (bytes)
    const int wbase = (lane << 9) ^ ((lane & 7) << 4) ^ (wave << 6);  // fill: ch = 4w+c
    int rbase[2];
    rbase[0] = (l5 << 9) ^ ((l5 & 7) << 4) ^ (half << 4);             // read: ch = 2ks+half
    rbase[1] = rbase[0] + (32 << 9);

    // fill one 16B chunk: row = lane, chunk = 4*wave + c (c compile-time).
    // t in revolutions, < 10 rev << 256-rev valid domain of v_sin/v_cos.
    auto fill_chunk = [&](char* eb, int c, float xr) {
        const float DC[4] = {1.0f, 0.7498942093324559f, 0.5623413251903491f,
                             0.4216965034285822f};
        const float t0 = xr * DC[c];
        const float t[4] = {t0, t0 * 0.9305720409297085f,
                            t0 * 0.8659643233600653f, t0 * 0.8058421877614819f};
        uint4v w;
        #pragma unroll
        for (int j = 0; j < 4; ++j)
            w[j] = pack_sc(__builtin_amdgcn_sinf(t[j]), __builtin_amdgcn_cosf(t[j]));
        *(uint4v*)(eb + (wbase ^ (c << 4))) = w;
    };

    // ---- W strip (one type) in registers: 16 ks x short8 = 64 VGPRs
    short8 bw[16];
    auto loadW = [&](int t) {
        const unsigned short* wr = wbf + t * (HH * HH) + col * HH + half * 8;
        #pragma unroll
        for (int ks = 0; ks < 16; ++ks)
            bw[ks] = *(const short8*)(wr + ks * 16);
    };

    loadW(0);
    __syncthreads();  // xsd/xsa ready
    // prologue: fill buf0 for phase 0 (point 0, d-type)
    {
        const float xr = xsd[0][lane] * cw;
        #pragma unroll
        for (int c = 0; c < 4; ++c) fill_chunk((char*)E[0], c, xr);
    }

    // 16 phases: 0..7 = d-pass (pt 0..7), 8..15 = a-pass (pt 0..7)
    #pragma unroll 1
    for (int ph = 0; ph < 16; ++ph) {
        __syncthreads();  // E[ph&1] filled; E[ph&1 ^1] free
        const int b = ph & 1;
        if (ph == 8) loadW(1);  // switch to Wa for the a-pass

        const bool dofill = (ph + 1) < 16;
        float xr = 0.f;
        if (dofill) {
            const int pn = (ph + 1) & 7;
            xr = ((ph + 1) < 8 ? xsd[pn][lane] : xsa[pn][lane]) * cw;
        }

        const char* ebC = (const char*)E[b];
        char* ebN = (char*)E[b ^ 1];

        f32x16 acc[2];
        #pragma unroll
        for (int mt = 0; mt < 2; ++mt)
            #pragma unroll
            for (int r = 0; r < 16; ++r) acc[mt][r] = 0.f;

        #pragma unroll
        for (int ks = 0; ks < 16; ++ks) {
            if (dofill && (ks & 3) == 0) fill_chunk(ebN, ks >> 2, xr);
            #pragma unroll
            for (int mt = 0; mt < 2; ++mt) {
                const short8 afr = *(const short8*)(ebC + (rbase[mt] ^ (ks << 5)));
                acc[mt] = __builtin_amdgcn_mfma_f32_32x32x16_bf16(
                    afr, bw[ks], acc[mt], 0, 0, 0);
            }
        }

        // epilogue: max over 64 anchors. C layout: col=lane&31, rows split by
        // lane-half; 2 mt tiles x 16 regs cover 32 rows; shfl_down(32) merges
        // halves. Valid on lanes 0..31.
        const int q = ph & 7;
        float m = acc[0][0];
        #pragma unroll
        for (int r = 1; r < 16; ++r) m = fmaxf(m, acc[0][r]);
        #pragma unroll
        for (int r = 0; r < 16; ++r) m = fmaxf(m, acc[1][r]);
        m = fmaxf(m, __shfl_down(m, 32));
        if (lane < 32) {
            if (ph < 8) dms[q][col] = m;
            else out[(base + q) * HH + col] = m + dms[q][col] + bias;
        }
    }
}

extern "C" void kernel_launch(void* const* d_in, const int* in_sizes, int n_in,
                              void* d_out, int out_size, void* d_ws, size_t ws_size,
                              hipStream_t stream) {
    const float* points  = (const float*)d_in[0];
    const float* anchors = (const float*)d_in[1];
    // d_in[2] = cor_score: unused by the reference
    const float* Wa = (const float*)d_in[3];
    const float* ba = (const float*)d_in[4];
    const float* Wd = (const float*)d_in[5];
    const float* bd = (const float*)d_in[6];

    unsigned short* wbf = (unsigned short*)d_ws;  // 256 KB: Wd|Wa bf16

    hipLaunchKernelGGL(prep_w_kernel, dim3(256), dim3(256), 0, stream, Wa, Wd, wbf);
    hipLaunchKernelGGL(cgse_main, dim3(NPTS / P_PTS), dim3(512), 0, stream,
                       points, anchors, wbf, ba, bd, (float*)d_out);
}